// Round 7
// baseline (104.194 us; speedup 1.0000x reference)
//
#include <hip/hip_runtime.h>

// Closing = erosion(identity) ∘ dilation(sum over CIN=3), K=5, edge padding.
// v7 = v6 (packed-f16 compute, fp32 in/out) with ROCm-proof packed ops:
//   clang ext_vector _Float16 + __builtin_elementwise_max/min -> v_pk_{add,max,min}_f16
//  - tile 32x64, grid (4,8,64); dilation 324 tasks 1rx8c, erosion 256 tasks 1rx8c
//  - aligned b128/b64 half2 reads + v_alignbit funnel shifts for odd offsets
//  - erosion-pad replication fused into dilation writeback (branch-free erosion)
//  - no state across barriers (v2 lesson), all-thread phases (v3/v4 lesson)

typedef _Float16 h2 __attribute__((ext_vector_type(2)));

namespace {
constexpr int HH = 256, WW = 256, CI = 3;
constexpr int XS2 = 36;           // sx row stride (half2 units)
constexpr int CH2 = 40 * XS2;     // per-channel half2 count (1440)
constexpr int DS2 = 36;           // sdil row stride (half2 units)
}

struct __align__(16) h2x4 { h2 a, b, c, d; };
struct __align__(8)  h2x2 { h2 a, b; };

__device__ __forceinline__ h2 pmax(h2 a, h2 b) { return __builtin_elementwise_max(a, b); }
__device__ __forceinline__ h2 pmin(h2 a, h2 b) { return __builtin_elementwise_min(a, b); }

__device__ __forceinline__ h2 shr1(h2 lo, h2 hi) {
    // (lo.y, hi.x) — one v_alignbit_b32
    unsigned a = __builtin_bit_cast(unsigned, lo);
    unsigned b = __builtin_bit_cast(unsigned, hi);
    unsigned r = (a >> 16) | (b << 16);
    return __builtin_bit_cast(h2, r);
}

__device__ __forceinline__ void dtaps(h2& m0, h2& m1, h2& m2, h2& m3,
                                      const h2x4 A, const h2x2 B,
                                      h2 w0, h2 w1, h2 w2, h2 w3, h2 w4) {
    const h2 s0 = shr1(A.a, A.b), s1 = shr1(A.b, A.c), s2 = shr1(A.c, A.d),
             s3 = shr1(A.d, B.a), s4 = shr1(B.a, B.b);
    m0 = pmax(m0, pmax(pmax(A.a + w0, s0 + w1), pmax(A.b + w2, pmax(s1 + w3, A.c + w4))));
    m1 = pmax(m1, pmax(pmax(A.b + w0, s1 + w1), pmax(A.c + w2, pmax(s2 + w3, A.d + w4))));
    m2 = pmax(m2, pmax(pmax(A.c + w0, s2 + w1), pmax(A.d + w2, pmax(s3 + w3, B.a + w4))));
    m3 = pmax(m3, pmax(pmax(A.d + w0, s3 + w1), pmax(B.a + w2, pmax(s4 + w3, B.b + w4))));
}

__device__ __forceinline__ void etaps(h2& m0, h2& m1, h2& m2, h2& m3,
                                      const h2x4 A, const h2x2 B,
                                      h2 w0, h2 w1, h2 w2, h2 w3, h2 w4) {
    const h2 s0 = shr1(A.a, A.b), s1 = shr1(A.b, A.c), s2 = shr1(A.c, A.d),
             s3 = shr1(A.d, B.a), s4 = shr1(B.a, B.b);
    m0 = pmin(m0, pmin(pmin(A.a + w0, s0 + w1), pmin(A.b + w2, pmin(s1 + w3, A.c + w4))));
    m1 = pmin(m1, pmin(pmin(A.b + w0, s1 + w1), pmin(A.c + w2, pmin(s2 + w3, A.d + w4))));
    m2 = pmin(m2, pmin(pmin(A.c + w0, s2 + w1), pmin(A.d + w2, pmin(s3 + w3, B.a + w4))));
    m3 = pmin(m3, pmin(pmin(A.d + w0, s3 + w1), pmin(B.a + w2, pmin(s4 + w3, B.b + w4))));
}

__global__ __launch_bounds__(256, 6)
void closing_v7(const float* __restrict__ x, const float* __restrict__ wd,
                const float* __restrict__ we, float* __restrict__ out) {
    __shared__ __align__(16) h2 sx2[CI * CH2 + 8];   // 17312 B
    __shared__ __align__(16) h2 sd2[36 * DS2];       //  5184 B

    const int tid = threadIdx.x;
    const int bx = blockIdx.x, by = blockIdx.y, z = blockIdx.z;
    const int o = z & 15, b = z >> 4;
    const int i0 = by * 32, j0 = bx * 64;
    const float* xb = x + (size_t)b * (CI * HH * WW);

    // ---- stage x: 3ch x 40 rows x 72 cols as half2; float4 loads + cvt ----
#pragma unroll
    for (int k = 0; k < 9; ++k) {
        const int idx = tid + (k << 8);
        if (idx < 2160) {
            const int c   = idx / 720;
            const int rem = idx - c * 720;
            const int r   = rem / 18;
            const int q   = rem - r * 18;
            const int gi  = min(max(i0 - 4 + r, 0), HH - 1);
            const int gj0 = j0 - 4 + (q << 2);
            const float* rowp = xb + c * (HH * WW) + (gi << 8);
            float4 v;
            if (gj0 < 0)        { const float t = rowp[0];      v = make_float4(t, t, t, t); }
            else if (gj0 > 252) { const float t = rowp[WW - 1]; v = make_float4(t, t, t, t); }
            else                  v = *(const float4*)(rowp + gj0);
            h2x2 hw;
            hw.a = h2{(_Float16)v.x, (_Float16)v.y};
            hw.b = h2{(_Float16)v.z, (_Float16)v.w};
            *(h2x2*)&sx2[c * CH2 + r * XS2 + (q << 1)] = hw;
        }
    }
    __syncthreads();

    // ---- dilation: 36 rows x 9 strips (8 cols) = 324 tasks ----
    for (int t = tid; t < 324; t += 256) {
        const int rr = t / 9, s = t - rr * 9;
        const int colh = s << 2;
        h2 acc0 = (h2)(_Float16)0.f, acc1 = acc0, acc2 = acc0, acc3 = acc0;
#pragma unroll
        for (int c = 0; c < CI; ++c) {
            const float* wr = wd + (o * CI + c) * 25;   // uniform -> s_load
            h2 wk[25];
#pragma unroll
            for (int i = 0; i < 25; ++i) wk[i] = (h2)(_Float16)wr[i];
            h2 m0 = (h2)(_Float16)-60000.f, m1 = m0, m2 = m0, m3 = m0;
            const int base = c * CH2 + rr * XS2 + colh;
#pragma unroll
            for (int r5 = 0; r5 < 5; ++r5) {
                const h2x4 A = *(const h2x4*)&sx2[base + r5 * XS2];
                const h2x2 B = *(const h2x2*)&sx2[base + r5 * XS2 + 4];
                dtaps(m0, m1, m2, m3, A, B,
                      wk[r5*5+0], wk[r5*5+1], wk[r5*5+2], wk[r5*5+3], wk[r5*5+4]);
            }
            acc0 = acc0 + m0; acc1 = acc1 + m1; acc2 = acc2 + m2; acc3 = acc3 + m3;
        }
        // erosion-input pad replication (fused)
        if (bx == 0 && s == 0) acc0 = (h2)acc1.x;   // cols 0,1 <- col 2
        if (bx == 3 && s == 8) acc1 = (h2)acc0.y;   // cols 66,67 <- col 65
        bool store = true;
        if (by == 0 && rr < 2)  store = false;      // phantom rows written by rr==2
        if (by == 7 && rr > 33) store = false;
        if (store) {
            const int db = rr * DS2 + colh;
            if (s < 8) { h2x4 w4v = {acc0, acc1, acc2, acc3}; *(h2x4*)&sd2[db] = w4v; }
            else       { h2x2 w2v = {acc0, acc1};             *(h2x2*)&sd2[db] = w2v; }
            if (by == 0 && rr == 2) {
#pragma unroll
                for (int pr = 0; pr < 2; ++pr) {
                    const int pb = pr * DS2 + colh;
                    if (s < 8) { h2x4 w4v = {acc0, acc1, acc2, acc3}; *(h2x4*)&sd2[pb] = w4v; }
                    else       { h2x2 w2v = {acc0, acc1};             *(h2x2*)&sd2[pb] = w2v; }
                }
            }
            if (by == 7 && rr == 33) {
#pragma unroll
                for (int pr = 34; pr < 36; ++pr) {
                    const int pb = pr * DS2 + colh;
                    if (s < 8) { h2x4 w4v = {acc0, acc1, acc2, acc3}; *(h2x4*)&sd2[pb] = w4v; }
                    else       { h2x2 w2v = {acc0, acc1};             *(h2x2*)&sd2[pb] = w2v; }
                }
            }
        }
    }
    __syncthreads();

    // ---- erosion: 32 rows x 8 strips = 256 tasks, branch-free ----
    {
        const int r = tid >> 3, s = tid & 7;
        const float* ew = we + o * 25;               // uniform -> s_load
        h2 wk[25];
#pragma unroll
        for (int i = 0; i < 25; ++i) wk[i] = (h2)(_Float16)(-ew[i]);   // negated
        h2 m0 = (h2)(_Float16)60000.f, m1 = m0, m2 = m0, m3 = m0;
        const int base = r * DS2 + (s << 2);
#pragma unroll
        for (int r5 = 0; r5 < 5; ++r5) {
            const h2x4 A = *(const h2x4*)&sd2[base + r5 * DS2];
            const h2x2 B = *(const h2x2*)&sd2[base + r5 * DS2 + 4];
            etaps(m0, m1, m2, m3, A, B,
                  wk[r5*5+0], wk[r5*5+1], wk[r5*5+2], wk[r5*5+3], wk[r5*5+4]);
        }
        float* op = &out[((size_t)z << 16) + ((size_t)(i0 + r) << 8) + j0 + (s << 3)];
        *(float4*)op       = make_float4((float)m0.x, (float)m0.y, (float)m1.x, (float)m1.y);
        *(float4*)(op + 4) = make_float4((float)m2.x, (float)m2.y, (float)m3.x, (float)m3.y);
    }
}

extern "C" void kernel_launch(void* const* d_in, const int* in_sizes, int n_in,
                              void* d_out, int out_size, void* d_ws, size_t ws_size,
                              hipStream_t stream) {
    const float* x  = (const float*)d_in[0];   // (4,3,256,256)
    const float* wd = (const float*)d_in[1];   // (16,3,5,5)
    const float* we = (const float*)d_in[2];   // (16,5,5)
    float* out = (float*)d_out;                // (4,16,256,256)

    dim3 grid(4, 8, 64);                       // 32x64 tiles
    closing_v7<<<grid, dim3(256), 0, stream>>>(x, wd, we, out);
}

// Round 8
// 90.946 us; speedup vs baseline: 1.1457x; 1.1457x over previous
//
#include <hip/hip_runtime.h>

// Closing = erosion(identity) ∘ dilation(sum over CIN=3), K=5, edge padding.
// v8 = v7 (packed-f16 compute, fp32 in/out) minus the spill:
//   - __launch_bounds__(256,4): 128-VGPR cap (v7's (256,6) capped at ~42 -> 73MB
//     scratch traffic; WRITE_SIZE 66MB was the tell)
//   - weights converted 5-per-row inside the tap loop (peak live 5 regs, not 25)
//  - tile 32x64, grid (4,8,64); dilation 324 tasks 1rx8c, erosion 256 tasks 1rx8c
//  - aligned b128/b64 half2 reads + v_alignbit funnel shifts for odd offsets
//  - erosion-pad replication fused into dilation writeback (branch-free erosion)

typedef _Float16 h2 __attribute__((ext_vector_type(2)));

namespace {
constexpr int HH = 256, WW = 256, CI = 3;
constexpr int XS2 = 36;           // sx row stride (half2 units)
constexpr int CH2 = 40 * XS2;     // per-channel half2 count (1440)
constexpr int DS2 = 36;           // sdil row stride (half2 units)
}

struct __align__(16) h2x4 { h2 a, b, c, d; };
struct __align__(8)  h2x2 { h2 a, b; };

__device__ __forceinline__ h2 pmax(h2 a, h2 b) { return __builtin_elementwise_max(a, b); }
__device__ __forceinline__ h2 pmin(h2 a, h2 b) { return __builtin_elementwise_min(a, b); }

__device__ __forceinline__ h2 shr1(h2 lo, h2 hi) {
    // (lo.y, hi.x) — one v_alignbit_b32
    unsigned a = __builtin_bit_cast(unsigned, lo);
    unsigned b = __builtin_bit_cast(unsigned, hi);
    unsigned r = (a >> 16) | (b << 16);
    return __builtin_bit_cast(h2, r);
}

__device__ __forceinline__ void dtaps(h2& m0, h2& m1, h2& m2, h2& m3,
                                      const h2x4 A, const h2x2 B,
                                      h2 w0, h2 w1, h2 w2, h2 w3, h2 w4) {
    const h2 s0 = shr1(A.a, A.b), s1 = shr1(A.b, A.c), s2 = shr1(A.c, A.d),
             s3 = shr1(A.d, B.a), s4 = shr1(B.a, B.b);
    m0 = pmax(m0, pmax(pmax(A.a + w0, s0 + w1), pmax(A.b + w2, pmax(s1 + w3, A.c + w4))));
    m1 = pmax(m1, pmax(pmax(A.b + w0, s1 + w1), pmax(A.c + w2, pmax(s2 + w3, A.d + w4))));
    m2 = pmax(m2, pmax(pmax(A.c + w0, s2 + w1), pmax(A.d + w2, pmax(s3 + w3, B.a + w4))));
    m3 = pmax(m3, pmax(pmax(A.d + w0, s3 + w1), pmax(B.a + w2, pmax(s4 + w3, B.b + w4))));
}

__device__ __forceinline__ void etaps(h2& m0, h2& m1, h2& m2, h2& m3,
                                      const h2x4 A, const h2x2 B,
                                      h2 w0, h2 w1, h2 w2, h2 w3, h2 w4) {
    const h2 s0 = shr1(A.a, A.b), s1 = shr1(A.b, A.c), s2 = shr1(A.c, A.d),
             s3 = shr1(A.d, B.a), s4 = shr1(B.a, B.b);
    m0 = pmin(m0, pmin(pmin(A.a + w0, s0 + w1), pmin(A.b + w2, pmin(s1 + w3, A.c + w4))));
    m1 = pmin(m1, pmin(pmin(A.b + w0, s1 + w1), pmin(A.c + w2, pmin(s2 + w3, A.d + w4))));
    m2 = pmin(m2, pmin(pmin(A.c + w0, s2 + w1), pmin(A.d + w2, pmin(s3 + w3, B.a + w4))));
    m3 = pmin(m3, pmin(pmin(A.d + w0, s3 + w1), pmin(B.a + w2, pmin(s4 + w3, B.b + w4))));
}

__global__ __launch_bounds__(256, 4)
void closing_v8(const float* __restrict__ x, const float* __restrict__ wd,
                const float* __restrict__ we, float* __restrict__ out) {
    __shared__ __align__(16) h2 sx2[CI * CH2 + 8];   // 17312 B
    __shared__ __align__(16) h2 sd2[36 * DS2];       //  5184 B

    const int tid = threadIdx.x;
    const int bx = blockIdx.x, by = blockIdx.y, z = blockIdx.z;
    const int o = z & 15, b = z >> 4;
    const int i0 = by * 32, j0 = bx * 64;
    const float* xb = x + (size_t)b * (CI * HH * WW);

    // ---- stage x: 3ch x 40 rows x 72 cols as half2; float4 loads + cvt ----
#pragma unroll
    for (int k = 0; k < 9; ++k) {
        const int idx = tid + (k << 8);
        if (idx < 2160) {
            const int c   = idx / 720;
            const int rem = idx - c * 720;
            const int r   = rem / 18;
            const int q   = rem - r * 18;
            const int gi  = min(max(i0 - 4 + r, 0), HH - 1);
            const int gj0 = j0 - 4 + (q << 2);
            const float* rowp = xb + c * (HH * WW) + (gi << 8);
            float4 v;
            if (gj0 < 0)        { const float t = rowp[0];      v = make_float4(t, t, t, t); }
            else if (gj0 > 252) { const float t = rowp[WW - 1]; v = make_float4(t, t, t, t); }
            else                  v = *(const float4*)(rowp + gj0);
            h2x2 hw;
            hw.a = h2{(_Float16)v.x, (_Float16)v.y};
            hw.b = h2{(_Float16)v.z, (_Float16)v.w};
            *(h2x2*)&sx2[c * CH2 + r * XS2 + (q << 1)] = hw;
        }
    }
    __syncthreads();

    // ---- dilation: 36 rows x 9 strips (8 cols) = 324 tasks ----
    for (int t = tid; t < 324; t += 256) {
        const int rr = t / 9, s = t - rr * 9;
        const int colh = s << 2;
        h2 acc0 = (h2)(_Float16)0.f, acc1 = acc0, acc2 = acc0, acc3 = acc0;
#pragma unroll
        for (int c = 0; c < CI; ++c) {
            const float* wr = wd + (o * CI + c) * 25;   // uniform -> s_load
            h2 m0 = (h2)(_Float16)-60000.f, m1 = m0, m2 = m0, m3 = m0;
            const int base = c * CH2 + rr * XS2 + colh;
#pragma unroll
            for (int r5 = 0; r5 < 5; ++r5) {
                const h2x4 A = *(const h2x4*)&sx2[base + r5 * XS2];
                const h2x2 B = *(const h2x2*)&sx2[base + r5 * XS2 + 4];
                const h2 w0 = (h2)(_Float16)wr[r5*5+0], w1 = (h2)(_Float16)wr[r5*5+1],
                         w2 = (h2)(_Float16)wr[r5*5+2], w3 = (h2)(_Float16)wr[r5*5+3],
                         w4 = (h2)(_Float16)wr[r5*5+4];
                dtaps(m0, m1, m2, m3, A, B, w0, w1, w2, w3, w4);
            }
            acc0 = acc0 + m0; acc1 = acc1 + m1; acc2 = acc2 + m2; acc3 = acc3 + m3;
        }
        // erosion-input pad replication (fused)
        if (bx == 0 && s == 0) acc0 = (h2)acc1.x;   // cols 0,1 <- col 2
        if (bx == 3 && s == 8) acc1 = (h2)acc0.y;   // cols 66,67 <- col 65
        bool store = true;
        if (by == 0 && rr < 2)  store = false;      // phantom rows written by rr==2
        if (by == 7 && rr > 33) store = false;
        if (store) {
            const int db = rr * DS2 + colh;
            if (s < 8) { h2x4 w4v = {acc0, acc1, acc2, acc3}; *(h2x4*)&sd2[db] = w4v; }
            else       { h2x2 w2v = {acc0, acc1};             *(h2x2*)&sd2[db] = w2v; }
            if (by == 0 && rr == 2) {
#pragma unroll
                for (int pr = 0; pr < 2; ++pr) {
                    const int pb = pr * DS2 + colh;
                    if (s < 8) { h2x4 w4v = {acc0, acc1, acc2, acc3}; *(h2x4*)&sd2[pb] = w4v; }
                    else       { h2x2 w2v = {acc0, acc1};             *(h2x2*)&sd2[pb] = w2v; }
                }
            }
            if (by == 7 && rr == 33) {
#pragma unroll
                for (int pr = 34; pr < 36; ++pr) {
                    const int pb = pr * DS2 + colh;
                    if (s < 8) { h2x4 w4v = {acc0, acc1, acc2, acc3}; *(h2x4*)&sd2[pb] = w4v; }
                    else       { h2x2 w2v = {acc0, acc1};             *(h2x2*)&sd2[pb] = w2v; }
                }
            }
        }
    }
    __syncthreads();

    // ---- erosion: 32 rows x 8 strips = 256 tasks, branch-free ----
    {
        const int r = tid >> 3, s = tid & 7;
        const float* ew = we + o * 25;               // uniform -> s_load
        h2 m0 = (h2)(_Float16)60000.f, m1 = m0, m2 = m0, m3 = m0;
        const int base = r * DS2 + (s << 2);
#pragma unroll
        for (int r5 = 0; r5 < 5; ++r5) {
            const h2x4 A = *(const h2x4*)&sd2[base + r5 * DS2];
            const h2x2 B = *(const h2x2*)&sd2[base + r5 * DS2 + 4];
            const h2 w0 = (h2)(_Float16)(-ew[r5*5+0]), w1 = (h2)(_Float16)(-ew[r5*5+1]),
                     w2 = (h2)(_Float16)(-ew[r5*5+2]), w3 = (h2)(_Float16)(-ew[r5*5+3]),
                     w4 = (h2)(_Float16)(-ew[r5*5+4]);
            etaps(m0, m1, m2, m3, A, B, w0, w1, w2, w3, w4);
        }
        float* op = &out[((size_t)z << 16) + ((size_t)(i0 + r) << 8) + j0 + (s << 3)];
        *(float4*)op       = make_float4((float)m0.x, (float)m0.y, (float)m1.x, (float)m1.y);
        *(float4*)(op + 4) = make_float4((float)m2.x, (float)m2.y, (float)m3.x, (float)m3.y);
    }
}

extern "C" void kernel_launch(void* const* d_in, const int* in_sizes, int n_in,
                              void* d_out, int out_size, void* d_ws, size_t ws_size,
                              hipStream_t stream) {
    const float* x  = (const float*)d_in[0];   // (4,3,256,256)
    const float* wd = (const float*)d_in[1];   // (16,3,5,5)
    const float* we = (const float*)d_in[2];   // (16,5,5)
    float* out = (float*)d_out;                // (4,16,256,256)

    dim3 grid(4, 8, 64);                       // 32x64 tiles
    closing_v8<<<grid, dim3(256), 0, stream>>>(x, wd, we, out);
}